// Round 8
// baseline (132.709 us; speedup 1.0000x reference)
//
#include <hip/hip_runtime.h>

#define N_NODES   50000
#define N_HEDGES  100000
#define E_EDGES   800000
#define F_IN      128
#define F_H       64
#define F_OUT     128

typedef __attribute__((ext_vector_type(8))) short short8;
typedef __attribute__((ext_vector_type(4))) float f32x4;
typedef _Float16 half2_t __attribute__((ext_vector_type(2)));
typedef _Float16 half4_t __attribute__((ext_vector_type(4)));

// float -> bf16 (RNE) and back, bit-level
__device__ __forceinline__ unsigned short f2bf(float f) {
    unsigned int u = __float_as_uint(f);
    return (unsigned short)((u + 0x7fffu + ((u >> 16) & 1u)) >> 16);
}
__device__ __forceinline__ float bf2f(unsigned short h) {
    return __uint_as_float(((unsigned int)h) << 16);
}

#define OFF_ITEMS (2 * (N_NODES + 1) + F_OUT * (F_IN + F_H))   // 124578
#define OFF_B     ((OFF_ITEMS + 255) / 256)                    // 487
#define CONV_NODE_F4  (N_NODES * 32)                           // 1,600,000
#define CONV_HEDGE_F4 (N_HEDGES * 16)                          // 1,600,000
#define CONV_B    ((CONV_NODE_F4 + CONV_HEDGE_F4 + 255) / 256) // 12500

// ---------------------------------------------------------------------------
// Kernel A: [blocks < OFF_B] edge-range binary search + W bf16 hi/lo split;
// [blocks >= OFF_B] fp32 -> fp16 conversion of both feature tables.
// ---------------------------------------------------------------------------
__global__ __launch_bounds__(256)
void offsets_kernel(const int* __restrict__ recv1, const int* __restrict__ recv2,
                    int* __restrict__ offs1, int* __restrict__ offs2,
                    const float* __restrict__ Wm, const float* __restrict__ Wsc,
                    unsigned short* __restrict__ wmhi, unsigned short* __restrict__ wmlo,
                    unsigned short* __restrict__ wshi, unsigned short* __restrict__ wslo,
                    const float* __restrict__ nf, const float* __restrict__ hf,
                    _Float16* __restrict__ nfH, _Float16* __restrict__ hfH) {
    if (blockIdx.x < OFF_B) {
        int t = blockIdx.x * blockDim.x + threadIdx.x;
        const int total = N_NODES + 1;
        if (t < total) {
            int r = t, lo = 0, hi = E_EDGES;
            while (lo < hi) { int mid = (lo + hi) >> 1; if (recv1[mid] < r) lo = mid + 1; else hi = mid; }
            offs1[r] = lo;
        } else if (t < 2 * total) {
            int r = t - total, lo = 0, hi = E_EDGES;
            while (lo < hi) { int mid = (lo + hi) >> 1; if (recv2[mid] < r) lo = mid + 1; else hi = mid; }
            offs2[r] = lo;
        } else if (t < OFF_ITEMS) {
            int idx = t - 2 * total;
            if (idx < F_OUT * F_IN) {
                float f = Wm[idx];
                unsigned short h = f2bf(f);
                wmhi[idx] = h; wmlo[idx] = f2bf(f - bf2f(h));
            } else {
                int i2 = idx - F_OUT * F_IN;
                float f = Wsc[i2];
                unsigned short h = f2bf(f);
                wshi[i2] = h; wslo[i2] = f2bf(f - bf2f(h));
            }
        }
    } else {
        int idx = (blockIdx.x - OFF_B) * 256 + threadIdx.x;   // float4 index
        if (idx < CONV_NODE_F4) {
            float4 v = *(const float4*)(nf + (size_t)idx * 4);
            half4_t h = { (_Float16)v.x, (_Float16)v.y, (_Float16)v.z, (_Float16)v.w };
            *(half4_t*)(nfH + (size_t)idx * 4) = h;
        } else {
            int i2 = idx - CONV_NODE_F4;
            if (i2 < CONV_HEDGE_F4) {
                float4 v = *(const float4*)(hf + (size_t)i2 * 4);
                half4_t h = { (_Float16)v.x, (_Float16)v.y, (_Float16)v.z, (_Float16)v.w };
                *(half4_t*)(hfH + (size_t)i2 * 4) = h;
            }
        }
    }
}

// ---------------------------------------------------------------------------
// Kernel B (fused gather + MFMA + tanh). Block = 1024 threads = 16 waves =
// 16 nodes (50000 = 3125 * 16, no guards). Phase 1: wave w gathers node
// (blk*16+w): node pipeline (lane = 2 fp16 features, 256B row reads) then
// hedge pipeline (lane = 1 feature, 128B rows); fp32 accumulate; write bf16
// hi/lo DIRECTLY into XOR-swizzled LDS tile + csums. One barrier. Phase 2:
// waves 0..7 (wave = 16 output features) run the dual hi/lo-split MFMA GEMM
// (Ah*Wh + Ah*Wl + Al*Wh) and store tanh((C1+cs1*bm)*(C2+cs2*bs)).
// A-frags streamed from LDS per-ks to keep VGPR <= 128 (16-wave residency).
// Kills the 38MB A-pack HBM round-trip and the separate gemm dispatch.
// ---------------------------------------------------------------------------
__global__ __launch_bounds__(1024)
void fused_gather_gemm(const _Float16* __restrict__ nfH, const _Float16* __restrict__ hfH,
                       const int* __restrict__ snd1, const float* __restrict__ cv1,
                       const int* __restrict__ o1,
                       const int* __restrict__ snd2, const float* __restrict__ cv2,
                       const int* __restrict__ o2,
                       const unsigned short* __restrict__ wmhi, const unsigned short* __restrict__ wmlo,
                       const unsigned short* __restrict__ wshi, const unsigned short* __restrict__ wslo,
                       const float* __restrict__ bm, const float* __restrict__ bs,
                       float* __restrict__ outp) {
    __shared__ __align__(16) char sA1[16 * 512];   // 8 KB bf16 hi|lo rows
    __shared__ __align__(16) char sA2[16 * 256];   // 4 KB
    __shared__ float sCs[16][2];

    const int t    = threadIdx.x;
    const int wid  = t >> 6;
    const int lane = t & 63;
    const int node = blockIdx.x * 16 + wid;        // always < N_NODES

    // ---- phase 1a: node-feature gather (fp32 accum over fp16 rows) ----
    {
        const int s = o1[node], e = o1[node + 1];
        float a0 = 0.f, a1 = 0.f, b0 = 0.f, b1 = 0.f, csA = 0.f, csB = 0.f;
        const _Float16* base = nfH + lane * 2;
        int i = s;
        for (; i + 8 <= e; i += 8) {
            int   s0 = snd1[i],   s1 = snd1[i+1], s2 = snd1[i+2], s3 = snd1[i+3];
            int   s4 = snd1[i+4], s5 = snd1[i+5], s6 = snd1[i+6], s7 = snd1[i+7];
            float c0 = cv1[i],    c1 = cv1[i+1],  c2 = cv1[i+2],  c3 = cv1[i+3];
            float c4 = cv1[i+4],  c5 = cv1[i+5],  c6 = cv1[i+6],  c7 = cv1[i+7];
            half2_t v0 = *(const half2_t*)(base + (size_t)s0 * F_IN);
            half2_t v1 = *(const half2_t*)(base + (size_t)s1 * F_IN);
            half2_t v2 = *(const half2_t*)(base + (size_t)s2 * F_IN);
            half2_t v3 = *(const half2_t*)(base + (size_t)s3 * F_IN);
            half2_t v4 = *(const half2_t*)(base + (size_t)s4 * F_IN);
            half2_t v5 = *(const half2_t*)(base + (size_t)s5 * F_IN);
            half2_t v6 = *(const half2_t*)(base + (size_t)s6 * F_IN);
            half2_t v7 = *(const half2_t*)(base + (size_t)s7 * F_IN);
            a0 += c0 * (float)v0.x; a1 += c0 * (float)v0.y;
            a0 += c1 * (float)v1.x; a1 += c1 * (float)v1.y;
            a0 += c2 * (float)v2.x; a1 += c2 * (float)v2.y;
            a0 += c3 * (float)v3.x; a1 += c3 * (float)v3.y;
            b0 += c4 * (float)v4.x; b1 += c4 * (float)v4.y;
            b0 += c5 * (float)v5.x; b1 += c5 * (float)v5.y;
            b0 += c6 * (float)v6.x; b1 += c6 * (float)v6.y;
            b0 += c7 * (float)v7.x; b1 += c7 * (float)v7.y;
            csA += c0 + c1 + c2 + c3; csB += c4 + c5 + c6 + c7;
        }
        for (; i + 4 <= e; i += 4) {
            int   s0 = snd1[i],   s1 = snd1[i+1], s2 = snd1[i+2], s3 = snd1[i+3];
            float c0 = cv1[i],    c1 = cv1[i+1],  c2 = cv1[i+2],  c3 = cv1[i+3];
            half2_t v0 = *(const half2_t*)(base + (size_t)s0 * F_IN);
            half2_t v1 = *(const half2_t*)(base + (size_t)s1 * F_IN);
            half2_t v2 = *(const half2_t*)(base + (size_t)s2 * F_IN);
            half2_t v3 = *(const half2_t*)(base + (size_t)s3 * F_IN);
            a0 += c0 * (float)v0.x; a1 += c0 * (float)v0.y;
            a0 += c1 * (float)v1.x; a1 += c1 * (float)v1.y;
            b0 += c2 * (float)v2.x; b1 += c2 * (float)v2.y;
            b0 += c3 * (float)v3.x; b1 += c3 * (float)v3.y;
            csA += c0 + c1; csB += c2 + c3;
        }
        for (; i < e; ++i) {
            int sn = snd1[i]; float c = cv1[i];
            half2_t v = *(const half2_t*)(base + (size_t)sn * F_IN);
            a0 += c * (float)v.x; a1 += c * (float)v.y; csA += c;
        }
        a0 += b0; a1 += b1;
        unsigned short h0 = f2bf(a0), h1 = f2bf(a1);
        unsigned short l0 = f2bf(a0 - bf2f(h0)), l1 = f2bf(a1 - bf2f(h1));
        unsigned int hi = (unsigned int)h0 | ((unsigned int)h1 << 16);
        unsigned int lo = (unsigned int)l0 | ((unsigned int)l1 << 16);
        unsigned off = ((unsigned)(lane * 4)) ^ (((unsigned)wid & 7) << 4);
        *(unsigned int*)(sA1 + wid * 512 + off)       = hi;
        *(unsigned int*)(sA1 + wid * 512 + 256 + off) = lo;
        if (lane == 0) sCs[wid][0] = csA + csB;
    }

    // ---- phase 1b: hedge-feature gather ----
    {
        const int s = o2[node], e = o2[node + 1];
        float a = 0.f, b = 0.f, csA = 0.f, csB = 0.f;
        const _Float16* base = hfH + lane;
        int i = s;
        for (; i + 8 <= e; i += 8) {
            int   s0 = snd2[i],   s1 = snd2[i+1], s2 = snd2[i+2], s3 = snd2[i+3];
            int   s4 = snd2[i+4], s5 = snd2[i+5], s6 = snd2[i+6], s7 = snd2[i+7];
            float c0 = cv2[i],    c1 = cv2[i+1],  c2 = cv2[i+2],  c3 = cv2[i+3];
            float c4 = cv2[i+4],  c5 = cv2[i+5],  c6 = cv2[i+6],  c7 = cv2[i+7];
            float v0 = (float)base[(size_t)s0 * F_H], v1 = (float)base[(size_t)s1 * F_H];
            float v2 = (float)base[(size_t)s2 * F_H], v3 = (float)base[(size_t)s3 * F_H];
            float v4 = (float)base[(size_t)s4 * F_H], v5 = (float)base[(size_t)s5 * F_H];
            float v6 = (float)base[(size_t)s6 * F_H], v7 = (float)base[(size_t)s7 * F_H];
            a += c0 * v0; a += c1 * v1; a += c2 * v2; a += c3 * v3;
            b += c4 * v4; b += c5 * v5; b += c6 * v6; b += c7 * v7;
            csA += c0 + c1 + c2 + c3; csB += c4 + c5 + c6 + c7;
        }
        for (; i + 4 <= e; i += 4) {
            int   s0 = snd2[i],   s1 = snd2[i+1], s2 = snd2[i+2], s3 = snd2[i+3];
            float c0 = cv2[i],    c1 = cv2[i+1],  c2 = cv2[i+2],  c3 = cv2[i+3];
            float v0 = (float)base[(size_t)s0 * F_H], v1 = (float)base[(size_t)s1 * F_H];
            float v2 = (float)base[(size_t)s2 * F_H], v3 = (float)base[(size_t)s3 * F_H];
            a += c0 * v0; a += c1 * v1; b += c2 * v2; b += c3 * v3;
            csA += c0 + c1; csB += c2 + c3;
        }
        for (; i < e; ++i) {
            int sn = snd2[i]; float c = cv2[i];
            a += c * (float)base[(size_t)sn * F_H]; csA += c;
        }
        a += b;
        unsigned short h = f2bf(a);
        unsigned short l = f2bf(a - bf2f(h));
        unsigned off = ((unsigned)(lane * 2)) ^ (((unsigned)wid & 7) << 4);
        *(unsigned short*)(sA2 + wid * 256 + off)       = h;
        *(unsigned short*)(sA2 + wid * 256 + 128 + off) = l;
        if (lane == 0) sCs[wid][1] = csA + csB;
    }

    __syncthreads();
    if (wid >= 8) return;          // gather-only waves done (no barriers below)

    // ---- phase 2: single-tile dual MFMA + epilogue (wave = 16 features) ----
    const int g  = lane >> 4;      // k-group
    const int jl = lane & 15;      // A row / B row / D col
    const int j  = wid * 16 + jl;  // output feature

    short8 wm_h[4], wm_l[4], ws_h[2], ws_l[2];
    #pragma unroll
    for (int ks = 0; ks < 4; ++ks) {
        wm_h[ks] = *(const short8*)(wmhi + j * F_IN + ks * 32 + g * 8);
        wm_l[ks] = *(const short8*)(wmlo + j * F_IN + ks * 32 + g * 8);
    }
    #pragma unroll
    for (int ks = 0; ks < 2; ++ks) {
        ws_h[ks] = *(const short8*)(wshi + j * F_H + ks * 32 + g * 8);
        ws_l[ks] = *(const short8*)(wslo + j * F_H + ks * 32 + g * 8);
    }
    const float bmj = bm[j], bsj = bs[j];

    const unsigned sw = ((unsigned)jl & 7) << 4;
    f32x4 c1 = {0.f, 0.f, 0.f, 0.f}, c2 = {0.f, 0.f, 0.f, 0.f};
    #pragma unroll
    for (int ks = 0; ks < 4; ++ks) {
        unsigned cc = (((unsigned)(4 * ks + g)) << 4) ^ sw;
        short8 a1h = *(const short8*)(sA1 + jl * 512 + cc);
        short8 a1l = *(const short8*)(sA1 + jl * 512 + 256 + cc);
        c1 = __builtin_amdgcn_mfma_f32_16x16x32_bf16(a1h, wm_h[ks], c1, 0, 0, 0);
        c1 = __builtin_amdgcn_mfma_f32_16x16x32_bf16(a1h, wm_l[ks], c1, 0, 0, 0);
        c1 = __builtin_amdgcn_mfma_f32_16x16x32_bf16(a1l, wm_h[ks], c1, 0, 0, 0);
    }
    #pragma unroll
    for (int ks = 0; ks < 2; ++ks) {
        unsigned cc = (((unsigned)(4 * ks + g)) << 4) ^ sw;
        short8 a2h = *(const short8*)(sA2 + jl * 256 + cc);
        short8 a2l = *(const short8*)(sA2 + jl * 256 + 128 + cc);
        c2 = __builtin_amdgcn_mfma_f32_16x16x32_bf16(a2h, ws_h[ks], c2, 0, 0, 0);
        c2 = __builtin_amdgcn_mfma_f32_16x16x32_bf16(a2h, ws_l[ks], c2, 0, 0, 0);
        c2 = __builtin_amdgcn_mfma_f32_16x16x32_bf16(a2l, ws_h[ks], c2, 0, 0, 0);
    }

    const int n0 = blockIdx.x * 16;
    #pragma unroll
    for (int r = 0; r < 4; ++r) {
        int row = g * 4 + r;
        float v1 = c1[r] + sCs[row][0] * bmj;
        float v2 = c2[r] + sCs[row][1] * bsj;
        outp[(size_t)(n0 + row) * F_OUT + j] = tanhf(v1 * v2);
    }
}

// ---------------------------------------------------------------------------
extern "C" void kernel_launch(void* const* d_in, const int* in_sizes, int n_in,
                              void* d_out, int out_size, void* d_ws, size_t ws_size,
                              hipStream_t stream) {
    const float* node_features  = (const float*)d_in[0];
    const float* hedge_features = (const float*)d_in[1];
    const int*   node_senders   = (const int*)d_in[2];
    const int*   node_receivers = (const int*)d_in[3];
    const float* node_conv      = (const float*)d_in[4];
    const int*   h2n_senders    = (const int*)d_in[5];
    const int*   h2n_receivers  = (const int*)d_in[6];
    const float* h2n_conv       = (const float*)d_in[7];
    const float* W_msg          = (const float*)d_in[8];
    const float* b_msg          = (const float*)d_in[9];
    const float* W_scale        = (const float*)d_in[10];
    const float* b_scale        = (const float*)d_in[11];

    float* out = (float*)d_out;
    char*  ws  = (char*)d_ws;

    // ws layout (~26.3 MB; harness provided >= 39.3 MB in prior rounds)
    int*   offs1 = (int*)  (ws);                             //   200,016 B
    int*   offs2 = (int*)  (ws + 200016);                    //   200,016 B
    unsigned short* wmhi = (unsigned short*)(ws + 400032);   //    32,768 B
    unsigned short* wmlo = (unsigned short*)(ws + 432800);   //    32,768 B
    unsigned short* wshi = (unsigned short*)(ws + 465568);   //    16,384 B
    unsigned short* wslo = (unsigned short*)(ws + 481952);   //    16,384 B
    _Float16* nfH = (_Float16*)(ws + 498336);                // 12,800,000 B
    _Float16* hfH = (_Float16*)(ws + 13298336);              // 12,800,000 B

    offsets_kernel<<<OFF_B + CONV_B, 256, 0, stream>>>(
        node_receivers, h2n_receivers, offs1, offs2,
        W_msg, W_scale, wmhi, wmlo, wshi, wslo,
        node_features, hedge_features, nfH, hfH);

    fused_gather_gemm<<<N_NODES / 16, 1024, 0, stream>>>(
        nfH, hfH,
        node_senders, node_conv, offs1,
        h2n_senders, h2n_conv, offs2,
        wmhi, wmlo, wshi, wslo,
        b_msg, b_scale, out);
}

// Round 9
// 111.045 us; speedup vs baseline: 1.1951x; 1.1951x over previous
//
#include <hip/hip_runtime.h>

#define N_NODES   50000
#define N_HEDGES  100000
#define E_EDGES   800000
#define F_IN      128
#define F_H       64
#define F_OUT     128

typedef __attribute__((ext_vector_type(8))) short short8;
typedef __attribute__((ext_vector_type(4))) float f32x4;
typedef _Float16 half2_t __attribute__((ext_vector_type(2)));
typedef _Float16 half4_t __attribute__((ext_vector_type(4)));

// float -> bf16 (RNE) and back, bit-level
__device__ __forceinline__ unsigned short f2bf(float f) {
    unsigned int u = __float_as_uint(f);
    return (unsigned short)((u + 0x7fffu + ((u >> 16) & 1u)) >> 16);
}
__device__ __forceinline__ float bf2f(unsigned short h) {
    return __uint_as_float(((unsigned int)h) << 16);
}

#define OFF_ITEMS (2 * (N_NODES + 1) + F_OUT * (F_IN + F_H))   // 124578
#define OFF_B     ((OFF_ITEMS + 255) / 256)                    // 487
#define CONV_NODE_F4  (N_NODES * 32)                           // 1,600,000
#define CONV_HEDGE_F4 (N_HEDGES * 16)                          // 1,600,000
#define CONV_B    ((CONV_NODE_F4 + CONV_HEDGE_F4 + 255) / 256) // 12500

// ---------------------------------------------------------------------------
// Kernel A: [blocks < OFF_B] edge-range binary search + W bf16 hi/lo split;
// [blocks >= OFF_B] fp32 -> fp16 conversion of both feature tables.
// ---------------------------------------------------------------------------
__global__ __launch_bounds__(256)
void offsets_kernel(const int* __restrict__ recv1, const int* __restrict__ recv2,
                    int* __restrict__ offs1, int* __restrict__ offs2,
                    const float* __restrict__ Wm, const float* __restrict__ Wsc,
                    unsigned short* __restrict__ wmhi, unsigned short* __restrict__ wmlo,
                    unsigned short* __restrict__ wshi, unsigned short* __restrict__ wslo,
                    const float* __restrict__ nf, const float* __restrict__ hf,
                    _Float16* __restrict__ nfH, _Float16* __restrict__ hfH) {
    if (blockIdx.x < OFF_B) {
        int t = blockIdx.x * blockDim.x + threadIdx.x;
        const int total = N_NODES + 1;
        if (t < total) {
            int r = t, lo = 0, hi = E_EDGES;
            while (lo < hi) { int mid = (lo + hi) >> 1; if (recv1[mid] < r) lo = mid + 1; else hi = mid; }
            offs1[r] = lo;
        } else if (t < 2 * total) {
            int r = t - total, lo = 0, hi = E_EDGES;
            while (lo < hi) { int mid = (lo + hi) >> 1; if (recv2[mid] < r) lo = mid + 1; else hi = mid; }
            offs2[r] = lo;
        } else if (t < OFF_ITEMS) {
            int idx = t - 2 * total;
            if (idx < F_OUT * F_IN) {
                float f = Wm[idx];
                unsigned short h = f2bf(f);
                wmhi[idx] = h; wmlo[idx] = f2bf(f - bf2f(h));
            } else {
                int i2 = idx - F_OUT * F_IN;
                float f = Wsc[i2];
                unsigned short h = f2bf(f);
                wshi[i2] = h; wslo[i2] = f2bf(f - bf2f(h));
            }
        }
    } else {
        int idx = (blockIdx.x - OFF_B) * 256 + threadIdx.x;   // float4 index
        if (idx < CONV_NODE_F4) {
            float4 v = *(const float4*)(nf + (size_t)idx * 4);
            half4_t h = { (_Float16)v.x, (_Float16)v.y, (_Float16)v.z, (_Float16)v.w };
            *(half4_t*)(nfH + (size_t)idx * 4) = h;
        } else {
            int i2 = idx - CONV_NODE_F4;
            if (i2 < CONV_HEDGE_F4) {
                float4 v = *(const float4*)(hf + (size_t)i2 * 4);
                half4_t h = { (_Float16)v.x, (_Float16)v.y, (_Float16)v.z, (_Float16)v.w };
                *(half4_t*)(hfH + (size_t)i2 * 4) = h;
            }
        }
    }
}

// ---------------------------------------------------------------------------
// Gather helpers (4-edge chunk, 1-edge tail, bf16 hi/lo pack-out).
// ---------------------------------------------------------------------------
__device__ __forceinline__ void node4(const _Float16* base, const int* __restrict__ snd,
                                      const float* __restrict__ cv, int i,
                                      float& a0, float& a1, float& cs) {
    int   s0 = snd[i],  s1 = snd[i+1], s2 = snd[i+2], s3 = snd[i+3];
    float c0 = cv[i],   c1 = cv[i+1],  c2 = cv[i+2],  c3 = cv[i+3];
    half2_t v0 = *(const half2_t*)(base + (size_t)s0 * F_IN);
    half2_t v1 = *(const half2_t*)(base + (size_t)s1 * F_IN);
    half2_t v2 = *(const half2_t*)(base + (size_t)s2 * F_IN);
    half2_t v3 = *(const half2_t*)(base + (size_t)s3 * F_IN);
    a0 += c0 * (float)v0.x; a1 += c0 * (float)v0.y;
    a0 += c1 * (float)v1.x; a1 += c1 * (float)v1.y;
    a0 += c2 * (float)v2.x; a1 += c2 * (float)v2.y;
    a0 += c3 * (float)v3.x; a1 += c3 * (float)v3.y;
    cs += c0 + c1 + c2 + c3;
}
__device__ __forceinline__ void node1(const _Float16* base, const int* __restrict__ snd,
                                      const float* __restrict__ cv, int i,
                                      float& a0, float& a1, float& cs) {
    int sn = snd[i]; float c = cv[i];
    half2_t v = *(const half2_t*)(base + (size_t)sn * F_IN);
    a0 += c * (float)v.x; a1 += c * (float)v.y; cs += c;
}
__device__ __forceinline__ void hedge4(const _Float16* base, const int* __restrict__ snd,
                                       const float* __restrict__ cv, int i,
                                       float& a, float& cs) {
    int   s0 = snd[i],  s1 = snd[i+1], s2 = snd[i+2], s3 = snd[i+3];
    float c0 = cv[i],   c1 = cv[i+1],  c2 = cv[i+2],  c3 = cv[i+3];
    float v0 = (float)base[(size_t)s0 * F_H], v1 = (float)base[(size_t)s1 * F_H];
    float v2 = (float)base[(size_t)s2 * F_H], v3 = (float)base[(size_t)s3 * F_H];
    a += c0 * v0; a += c1 * v1; a += c2 * v2; a += c3 * v3;
    cs += c0 + c1 + c2 + c3;
}
__device__ __forceinline__ void hedge1(const _Float16* base, const int* __restrict__ snd,
                                       const float* __restrict__ cv, int i,
                                       float& a, float& cs) {
    int sn = snd[i]; float c = cv[i];
    a += c * (float)base[(size_t)sn * F_H]; cs += c;
}
__device__ __forceinline__ void pack_node(char* a1pack, int node, int lane, float a0, float a1) {
    unsigned short h0 = f2bf(a0), h1 = f2bf(a1);
    unsigned short l0 = f2bf(a0 - bf2f(h0)), l1 = f2bf(a1 - bf2f(h1));
    *(unsigned int*)(a1pack + (size_t)node * 512 + lane * 4)       = (unsigned)h0 | ((unsigned)h1 << 16);
    *(unsigned int*)(a1pack + (size_t)node * 512 + 256 + lane * 4) = (unsigned)l0 | ((unsigned)l1 << 16);
}
__device__ __forceinline__ void pack_hedge(char* a2pack, int node, int lane, float a) {
    unsigned short h = f2bf(a);
    unsigned short l = f2bf(a - bf2f(h));
    ((unsigned short*)(a2pack + (size_t)node * 256))[lane]       = h;
    ((unsigned short*)(a2pack + (size_t)node * 256 + 128))[lane] = l;
}

// ---------------------------------------------------------------------------
// Fused gather kernel, DUAL-NODE per wave (round-9 change): each wave owns
// TWO consecutive nodes and interleaves their edge streams 4+4 in the main
// loop -> ~8 independent row loads in flight across two dependency chains
// (round-7 single-node version idled ~56% of issue slots on one L3-latency
// chain). Receivers sorted => o[nodeB] == eA (one offset load saved).
// Blocks [0, N/8): node pipeline (lane = 2 fp16 feats, 256B row reads).
// Blocks [N/8, 2N/8): hedge pipeline (lane = 1 feat, 128B rows).
// fp32 accumulate; emits packed bf16 hi/lo rows + csums.
// a1pack aliases d_out (row n's bytes belong to node n both ways).
// ---------------------------------------------------------------------------
__global__ __launch_bounds__(256)
void gather_fused(const _Float16* __restrict__ nfH, const _Float16* __restrict__ hfH,
                  const int* __restrict__ snd1, const float* __restrict__ cv1,
                  const int* __restrict__ o1,
                  const int* __restrict__ snd2, const float* __restrict__ cv2,
                  const int* __restrict__ o2,
                  char* a1pack, char* __restrict__ a2pack,
                  float* __restrict__ cs1o, float* __restrict__ cs2o) {
    const int lane = threadIdx.x & 63;
    const int wid  = threadIdx.x >> 6;
    const int NB   = N_NODES / 8;                 // 6250 node-side blocks

    if (blockIdx.x < NB) {
        const int nodeA = blockIdx.x * 8 + wid * 2;
        const int nodeB = nodeA + 1;
        const _Float16* base = nfH + lane * 2;
        int iA = o1[nodeA];
        int eA = o1[nodeB];                       // == o1[nodeA+1]
        int iB = eA;
        int eB = o1[nodeB + 1];
        float aA0 = 0.f, aA1 = 0.f, csA = 0.f;
        float aB0 = 0.f, aB1 = 0.f, csB = 0.f;
        while (iA + 4 <= eA && iB + 4 <= eB) {    // dual-stream main loop
            node4(base, snd1, cv1, iA, aA0, aA1, csA);
            node4(base, snd1, cv1, iB, aB0, aB1, csB);
            iA += 4; iB += 4;
        }
        for (; iA + 4 <= eA; iA += 4) node4(base, snd1, cv1, iA, aA0, aA1, csA);
        for (; iA < eA; ++iA)         node1(base, snd1, cv1, iA, aA0, aA1, csA);
        for (; iB + 4 <= eB; iB += 4) node4(base, snd1, cv1, iB, aB0, aB1, csB);
        for (; iB < eB; ++iB)         node1(base, snd1, cv1, iB, aB0, aB1, csB);
        pack_node(a1pack, nodeA, lane, aA0, aA1);
        pack_node(a1pack, nodeB, lane, aB0, aB1);
        if (lane == 0) { cs1o[nodeA] = csA; cs1o[nodeB] = csB; }
    } else {
        const int nodeA = (blockIdx.x - NB) * 8 + wid * 2;
        const int nodeB = nodeA + 1;
        const _Float16* base = hfH + lane;
        int iA = o2[nodeA];
        int eA = o2[nodeB];
        int iB = eA;
        int eB = o2[nodeB + 1];
        float aA = 0.f, csA = 0.f, aB = 0.f, csB = 0.f;
        while (iA + 4 <= eA && iB + 4 <= eB) {
            hedge4(base, snd2, cv2, iA, aA, csA);
            hedge4(base, snd2, cv2, iB, aB, csB);
            iA += 4; iB += 4;
        }
        for (; iA + 4 <= eA; iA += 4) hedge4(base, snd2, cv2, iA, aA, csA);
        for (; iA < eA; ++iA)         hedge1(base, snd2, cv2, iA, aA, csA);
        for (; iB + 4 <= eB; iB += 4) hedge4(base, snd2, cv2, iB, aB, csB);
        for (; iB < eB; ++iB)         hedge1(base, snd2, cv2, iB, aB, csB);
        pack_hedge(a2pack, nodeA, lane, aA);
        pack_hedge(a2pack, nodeB, lane, aB);
        if (lane == 0) { cs2o[nodeA] = csA; cs2o[nodeB] = csB; }
    }
}

// ---------------------------------------------------------------------------
// FALLBACK gathers (fp32 tables) if ws too small for fp16 tables.
// ---------------------------------------------------------------------------
__global__ __launch_bounds__(256)
void gather_nodes_kernel(const float* __restrict__ nf, const int* __restrict__ senders,
                         const float* __restrict__ conv, const int* __restrict__ offs,
                         char* a1pack, float* __restrict__ csum_out) {
    const int lane = threadIdx.x & 63;
    const int node = blockIdx.x * 4 + (threadIdx.x >> 6);
    const int s = offs[node], e = offs[node + 1];
    float a0 = 0.f, a1 = 0.f, cs = 0.f;
    const float* base = nf + lane * 2;
    int i = s;
    for (; i + 4 <= e; i += 4) {
        int   s0 = senders[i],   s1 = senders[i+1], s2 = senders[i+2], s3 = senders[i+3];
        float c0 = conv[i],      c1 = conv[i+1],    c2 = conv[i+2],    c3 = conv[i+3];
        float2 v0 = *(const float2*)(base + s0 * F_IN);
        float2 v1 = *(const float2*)(base + s1 * F_IN);
        float2 v2 = *(const float2*)(base + s2 * F_IN);
        float2 v3 = *(const float2*)(base + s3 * F_IN);
        a0 += c0 * v0.x; a1 += c0 * v0.y;
        a0 += c1 * v1.x; a1 += c1 * v1.y;
        a0 += c2 * v2.x; a1 += c2 * v2.y;
        a0 += c3 * v3.x; a1 += c3 * v3.y;
        cs += c0 + c1 + c2 + c3;
    }
    for (; i < e; ++i) {
        int sn = senders[i]; float c = conv[i];
        float2 v = *(const float2*)(base + sn * F_IN);
        a0 += c * v.x; a1 += c * v.y; cs += c;
    }
    unsigned short h0 = f2bf(a0), h1 = f2bf(a1);
    unsigned short l0 = f2bf(a0 - bf2f(h0)), l1 = f2bf(a1 - bf2f(h1));
    unsigned int* hp = (unsigned int*)(a1pack + (size_t)node * 512);
    unsigned int* lp = (unsigned int*)(a1pack + (size_t)node * 512 + 256);
    hp[lane] = (unsigned int)h0 | ((unsigned int)h1 << 16);
    lp[lane] = (unsigned int)l0 | ((unsigned int)l1 << 16);
    if (lane == 0) csum_out[node] = cs;
}

__global__ __launch_bounds__(256)
void gather_hedges_kernel(const float* __restrict__ hf, const int* __restrict__ senders,
                          const float* __restrict__ conv, const int* __restrict__ offs,
                          char* __restrict__ a2pack, float* __restrict__ csum_out) {
    const int lane = threadIdx.x & 63;
    const int node = blockIdx.x * 4 + (threadIdx.x >> 6);
    const int s = offs[node], e = offs[node + 1];
    float a = 0.f, cs = 0.f;
    const float* base = hf + lane;
    int i = s;
    for (; i + 4 <= e; i += 4) {
        int   s0 = senders[i],   s1 = senders[i+1], s2 = senders[i+2], s3 = senders[i+3];
        float c0 = conv[i],      c1 = conv[i+1],    c2 = conv[i+2],    c3 = conv[i+3];
        float v0 = base[s0 * F_H], v1 = base[s1 * F_H];
        float v2 = base[s2 * F_H], v3 = base[s3 * F_H];
        a += c0 * v0; a += c1 * v1; a += c2 * v2; a += c3 * v3;
        cs += c0 + c1 + c2 + c3;
    }
    for (; i < e; ++i) {
        int sn = senders[i]; float c = conv[i];
        a += c * base[sn * F_H]; cs += c;
    }
    unsigned short h = f2bf(a);
    unsigned short l = f2bf(a - bf2f(h));
    ((unsigned short*)(a2pack + (size_t)node * 256))[lane]       = h;
    ((unsigned short*)(a2pack + (size_t)node * 256 + 128))[lane] = l;
    if (lane == 0) csum_out[node] = cs;
}

// ---------------------------------------------------------------------------
// Kernel 3 (MFMA, unchanged from round 7): bf16 hi/lo split dual GEMM + tanh.
// ---------------------------------------------------------------------------
__global__ __launch_bounds__(256)
void gemm_tanh_kernel(const char* a1pack,                       // aliases out!
                      const char* __restrict__ a2pack,
                      const float* __restrict__ csum1, const float* __restrict__ csum2,
                      const unsigned short* __restrict__ wmhi, const unsigned short* __restrict__ wmlo,
                      const unsigned short* __restrict__ wshi, const unsigned short* __restrict__ wslo,
                      const float* __restrict__ bm, const float* __restrict__ bs,
                      float* outp) {
    __shared__ __align__(16) char sA1[16 * 512];   // 8 KB (hi|lo per row)
    __shared__ __align__(16) char sA2[16 * 256];   // 4 KB
    __shared__ float sCs[16][2];

    const int t   = threadIdx.x;
    const int wid = t >> 6;
    const int l   = t & 63;
    const int g   = l >> 4;     // lane group (k-groups)
    const int jl  = l & 15;     // A-frag row / B-frag row / D col

    short8 wm_h[2][4], wm_l[2][4], ws_h[2][2], ws_l[2][2];
    float bmj[2], bsj[2];
    #pragma unroll
    for (int jt = 0; jt < 2; ++jt) {
        const int j = wid * 32 + jt * 16 + jl;
        #pragma unroll
        for (int ks = 0; ks < 4; ++ks) {
            wm_h[jt][ks] = *(const short8*)(wmhi + j * F_IN + ks * 32 + g * 8);
            wm_l[jt][ks] = *(const short8*)(wmlo + j * F_IN + ks * 32 + g * 8);
        }
        #pragma unroll
        for (int ks = 0; ks < 2; ++ks) {
            ws_h[jt][ks] = *(const short8*)(wshi + j * F_H + ks * 32 + g * 8);
            ws_l[jt][ks] = *(const short8*)(wslo + j * F_H + ks * 32 + g * 8);
        }
        bmj[jt] = bm[j]; bsj[jt] = bs[j];
    }

    #pragma unroll 1
    for (int ns = 0; ns < 4; ++ns) {
        const int n0 = blockIdx.x * 64 + ns * 16;
        #pragma unroll
        for (int it = 0; it < 2; ++it) {
            int fi = (it << 8) + t;
            int ci = fi & 31, row = fi >> 5;
            int nsrc = min(n0 + row, N_NODES - 1);
            float4 v = *(const float4*)(a1pack + (size_t)nsrc * 512 + ci * 16);
            *(float4*)(sA1 + row * 512 + (((unsigned)ci << 4) ^ (((unsigned)row & 7) << 4))) = v;
        }
        {
            int ci = t & 15, row = t >> 4;
            int nsrc = min(n0 + row, N_NODES - 1);
            float4 v = *(const float4*)(a2pack + (size_t)nsrc * 256 + ci * 16);
            *(float4*)(sA2 + row * 256 + (((unsigned)ci << 4) ^ (((unsigned)row & 7) << 4))) = v;
        }
        if (t < 16)      sCs[t][0]      = csum1[min(n0 + t, N_NODES - 1)];
        else if (t < 32) sCs[t - 16][1] = csum2[min(n0 + t - 16, N_NODES - 1)];
        __syncthreads();

        short8 a1h[4], a1l[4], a2h[2], a2l[2];
        const unsigned sw = ((unsigned)jl & 7) << 4;
        #pragma unroll
        for (int ks = 0; ks < 4; ++ks) {
            unsigned cc = (((unsigned)(4 * ks + g)) << 4) ^ sw;
            a1h[ks] = *(const short8*)(sA1 + jl * 512 + cc);
            a1l[ks] = *(const short8*)(sA1 + jl * 512 + 256 + cc);
        }
        #pragma unroll
        for (int ks = 0; ks < 2; ++ks) {
            unsigned cc = (((unsigned)(4 * ks + g)) << 4) ^ sw;
            a2h[ks] = *(const short8*)(sA2 + jl * 256 + cc);
            a2l[ks] = *(const short8*)(sA2 + jl * 256 + 128 + cc);
        }

        #pragma unroll
        for (int jt = 0; jt < 2; ++jt) {
            f32x4 c1 = {0.f, 0.f, 0.f, 0.f}, c2 = {0.f, 0.f, 0.f, 0.f};
            #pragma unroll
            for (int ks = 0; ks < 4; ++ks) {
                c1 = __builtin_amdgcn_mfma_f32_16x16x32_bf16(a1h[ks], wm_h[jt][ks], c1, 0, 0, 0);
                c1 = __builtin_amdgcn_mfma_f32_16x16x32_bf16(a1h[ks], wm_l[jt][ks], c1, 0, 0, 0);
                c1 = __builtin_amdgcn_mfma_f32_16x16x32_bf16(a1l[ks], wm_h[jt][ks], c1, 0, 0, 0);
            }
            #pragma unroll
            for (int ks = 0; ks < 2; ++ks) {
                c2 = __builtin_amdgcn_mfma_f32_16x16x32_bf16(a2h[ks], ws_h[jt][ks], c2, 0, 0, 0);
                c2 = __builtin_amdgcn_mfma_f32_16x16x32_bf16(a2h[ks], ws_l[jt][ks], c2, 0, 0, 0);
                c2 = __builtin_amdgcn_mfma_f32_16x16x32_bf16(a2l[ks], ws_h[jt][ks], c2, 0, 0, 0);
            }
            const int j = wid * 32 + jt * 16 + jl;
            #pragma unroll
            for (int r = 0; r < 4; ++r) {
                int row  = g * 4 + r;
                int node = n0 + row;
                if (node < N_NODES) {
                    float v1 = c1[r] + sCs[row][0] * bmj[jt];
                    float v2 = c2[r] + sCs[row][1] * bsj[jt];
                    outp[(size_t)node * F_OUT + j] = tanhf(v1 * v2);
                }
            }
        }
        __syncthreads();
    }
}

// ---------------------------------------------------------------------------
extern "C" void kernel_launch(void* const* d_in, const int* in_sizes, int n_in,
                              void* d_out, int out_size, void* d_ws, size_t ws_size,
                              hipStream_t stream) {
    const float* node_features  = (const float*)d_in[0];
    const float* hedge_features = (const float*)d_in[1];
    const int*   node_senders   = (const int*)d_in[2];
    const int*   node_receivers = (const int*)d_in[3];
    const float* node_conv      = (const float*)d_in[4];
    const int*   h2n_senders    = (const int*)d_in[5];
    const int*   h2n_receivers  = (const int*)d_in[6];
    const float* h2n_conv       = (const float*)d_in[7];
    const float* W_msg          = (const float*)d_in[8];
    const float* b_msg          = (const float*)d_in[9];
    const float* W_scale        = (const float*)d_in[10];
    const float* b_scale        = (const float*)d_in[11];

    float* out = (float*)d_out;
    char*  ws  = (char*)d_ws;

    // ws layout
    char*  A2pack = ws;                                      // 12,800,000 B
    float* Csum1  = (float*)(ws + 12800000);                 //    200,000 B
    float* Csum2  = (float*)(ws + 13000000);                 //    200,000 B
    int*   offs1  = (int*)  (ws + 13200000);                 //    200,016 B
    int*   offs2  = (int*)  (ws + 13400016);                 //    200,016 B
    unsigned short* wmhi = (unsigned short*)(ws + 13600032); //     32,768 B
    unsigned short* wmlo = (unsigned short*)(ws + 13632800); //     32,768 B
    unsigned short* wshi = (unsigned short*)(ws + 13665568); //     16,384 B
    unsigned short* wslo = (unsigned short*)(ws + 13681952); //     16,384 B
    _Float16* nfH = (_Float16*)(ws + 13698560);              // 12,800,000 B
    _Float16* hfH = (_Float16*)(ws + 26498560);              // 12,800,000 B
    const size_t WS_NEED_FAST = 39298560;
    char*  A1pack = (char*)d_out;                            // packed bf16 hi/lo, aliases out

    const bool fast = (ws_size >= WS_NEED_FAST);

    if (fast) {
        offsets_kernel<<<OFF_B + CONV_B, 256, 0, stream>>>(
            node_receivers, h2n_receivers, offs1, offs2,
            W_msg, W_scale, wmhi, wmlo, wshi, wslo,
            node_features, hedge_features, nfH, hfH);
        gather_fused<<<2 * (N_NODES / 8), 256, 0, stream>>>(
            nfH, hfH,
            node_senders, node_conv, offs1,
            h2n_senders, h2n_conv, offs2,
            A1pack, A2pack, Csum1, Csum2);
    } else {
        offsets_kernel<<<OFF_B, 256, 0, stream>>>(
            node_receivers, h2n_receivers, offs1, offs2,
            W_msg, W_scale, wmhi, wmlo, wshi, wslo,
            node_features, hedge_features, nfH, hfH);
        gather_nodes_kernel<<<N_NODES / 4, 256, 0, stream>>>(
            node_features, node_senders, node_conv, offs1, A1pack, Csum1);
        gather_hedges_kernel<<<N_NODES / 4, 256, 0, stream>>>(
            hedge_features, h2n_senders, h2n_conv, offs2, A2pack, Csum2);
    }

    gemm_tanh_kernel<<<(N_NODES + 63) / 64, 256, 0, stream>>>(
        A1pack, A2pack, Csum1, Csum2, wmhi, wmlo, wshi, wslo,
        b_msg, b_scale, out);
}